// Round 1
// baseline (830.260 us; speedup 1.0000x reference)
//
#include <hip/hip_runtime.h>

#define HH 512
#define WW 512
#define HWSZ (HH * WW)

// ---------------------------------------------------------------------------
// Pre-pass: transpose featuremap (C,H,W) -> (H,W,C) so one bilinear corner is
// a single aligned float4 load instead of 4 scattered scalar loads.
// ---------------------------------------------------------------------------
__global__ void fm_transpose(const float* __restrict__ fm, float* __restrict__ fmT) {
    int i = blockIdx.x * blockDim.x + threadIdx.x;
    if (i < HWSZ) {
        float4 v;
        v.x = fm[i];
        v.y = fm[HWSZ + i];
        v.z = fm[2 * HWSZ + i];
        v.w = fm[3 * HWSZ + i];
        reinterpret_cast<float4*>(fmT)[i] = v;
    }
}

// ---------------------------------------------------------------------------
// Fused grid_sample + 5-layer MLP. 2 points per thread so each (scalar-loaded,
// wave-uniform) weight feeds 2 FMAs. All fp32 (no fp32 MFMA on CDNA4; bf16
// would risk the 5.3e-3 absmax threshold).
// TR=true: fm is the (H,W,C) transposed copy (float4 gathers).
// TR=false: fm is the original (C,H,W) layout (16 scalar gathers) — fallback
// when ws_size < 4 MB.
// ---------------------------------------------------------------------------
template <bool TR>
__global__ __launch_bounds__(256) void mlp_fused(
    const float* __restrict__ x, const float* __restrict__ fm,
    const float* __restrict__ W1, const float* __restrict__ b1,
    const float* __restrict__ W2, const float* __restrict__ b2,
    const float* __restrict__ W3, const float* __restrict__ b3,
    const float* __restrict__ W4, const float* __restrict__ b4,
    const float* __restrict__ W5, const float* __restrict__ b5,
    float* __restrict__ out, int n)
{
    const long long t  = (long long)blockIdx.x * blockDim.x + threadIdx.x;
    const long long i0 = 2 * t;
    if (i0 >= n) return;
    const bool have2 = (i0 + 1 < n);

    // ---- load 2 points' coords (6 consecutive floats, 8B-aligned float2) ----
    float px[2][3];
    if (have2) {
        const float2* x2 = reinterpret_cast<const float2*>(x);
        float2 a = x2[3 * t], b = x2[3 * t + 1], c = x2[3 * t + 2];
        px[0][0] = a.x; px[0][1] = a.y; px[0][2] = b.x;
        px[1][0] = b.y; px[1][1] = c.x; px[1][2] = c.y;
    } else {
        px[0][0] = x[3 * i0]; px[0][1] = x[3 * i0 + 1]; px[0][2] = x[3 * i0 + 2];
        px[1][0] = px[0][0];  px[1][1] = px[0][1];      px[1][2] = px[0][2];
    }

    // ---- bilinear sample, border clamp (mirrors reference arithmetic) ----
    float feat[2][4];
#pragma unroll
    for (int p = 0; p < 2; ++p) {
        float gx = px[p][0] * 2.f - 1.f;
        float gy = px[p][1] * 2.f - 1.f;
        float fx = ((gx + 1.f) * (float)WW - 1.f) * 0.5f;
        float fy = ((gy + 1.f) * (float)HH - 1.f) * 0.5f;
        fx = fminf(fmaxf(fx, 0.f), (float)(WW - 1));
        fy = fminf(fmaxf(fy, 0.f), (float)(HH - 1));
        float x0f = floorf(fx), y0f = floorf(fy);
        float wx = fx - x0f, wy = fy - y0f;
        int ix0 = (int)x0f, iy0 = (int)y0f;
        int ix1 = min(ix0 + 1, WW - 1);
        int iy1 = min(iy0 + 1, HH - 1);
        float w00 = (1.f - wy) * (1.f - wx);
        float w01 = (1.f - wy) * wx;
        float w10 = wy * (1.f - wx);
        float w11 = wy * wx;
        if (TR) {
            const float4* fmT = reinterpret_cast<const float4*>(fm);
            float4 v00 = fmT[iy0 * WW + ix0];
            float4 v01 = fmT[iy0 * WW + ix1];
            float4 v10 = fmT[iy1 * WW + ix0];
            float4 v11 = fmT[iy1 * WW + ix1];
            feat[p][0] = v00.x * w00 + v01.x * w01 + v10.x * w10 + v11.x * w11;
            feat[p][1] = v00.y * w00 + v01.y * w01 + v10.y * w10 + v11.y * w11;
            feat[p][2] = v00.z * w00 + v01.z * w01 + v10.z * w10 + v11.z * w11;
            feat[p][3] = v00.w * w00 + v01.w * w01 + v10.w * w10 + v11.w * w11;
        } else {
#pragma unroll
            for (int ch = 0; ch < 4; ++ch) {
                const float* f = fm + ch * HWSZ;
                feat[p][ch] = f[iy0 * WW + ix0] * w00 + f[iy0 * WW + ix1] * w01 +
                              f[iy1 * WW + ix0] * w10 + f[iy1 * WW + ix1] * w11;
            }
        }
    }

    // ---- MLP: weights are wave-uniform reads -> SGPRs, v_fmac v,s,v ----
    float in0[7] = {px[0][0], px[0][1], px[0][2], feat[0][0], feat[0][1], feat[0][2], feat[0][3]};
    float in1[7] = {px[1][0], px[1][1], px[1][2], feat[1][0], feat[1][1], feat[1][2], feat[1][3]};
    float h0[16], h1[16], g0[16], g1[16];

    // layer 1: 7 -> 16, relu
#pragma unroll
    for (int j = 0; j < 16; ++j) {
        float s0 = b1[j], s1 = s0;
#pragma unroll
        for (int k = 0; k < 7; ++k) {
            float w = W1[k * 16 + j];
            s0 = fmaf(in0[k], w, s0);
            s1 = fmaf(in1[k], w, s1);
        }
        h0[j] = fmaxf(s0, 0.f);
        h1[j] = fmaxf(s1, 0.f);
    }

#define LAYER16(Wp, bp, src0, src1, dst0, dst1)                   \
    _Pragma("unroll")                                             \
    for (int j = 0; j < 16; ++j) {                                \
        float s0 = (bp)[j], s1 = s0;                              \
        _Pragma("unroll")                                         \
        for (int k = 0; k < 16; ++k) {                            \
            float w = (Wp)[k * 16 + j];                           \
            s0 = fmaf((src0)[k], w, s0);                          \
            s1 = fmaf((src1)[k], w, s1);                          \
        }                                                         \
        (dst0)[j] = fmaxf(s0, 0.f);                               \
        (dst1)[j] = fmaxf(s1, 0.f);                               \
    }

    LAYER16(W2, b2, h0, h1, g0, g1)
    LAYER16(W3, b3, g0, g1, h0, h1)
    LAYER16(W4, b4, h0, h1, g0, g1)
#undef LAYER16

    // layer 5: 16 -> 3, no relu
    float o0[3], o1[3];
#pragma unroll
    for (int j = 0; j < 3; ++j) {
        float s0 = b5[j], s1 = s0;
#pragma unroll
        for (int k = 0; k < 16; ++k) {
            float w = W5[k * 3 + j];
            s0 = fmaf(g0[k], w, s0);
            s1 = fmaf(g1[k], w, s1);
        }
        o0[j] = s0;
        o1[j] = s1;
    }

    // ---- store (6 consecutive floats as 3x float2) ----
    if (have2) {
        float2* out2 = reinterpret_cast<float2*>(out);
        out2[3 * t]     = make_float2(o0[0], o0[1]);
        out2[3 * t + 1] = make_float2(o0[2], o1[0]);
        out2[3 * t + 2] = make_float2(o1[1], o1[2]);
    } else {
        out[3 * i0] = o0[0]; out[3 * i0 + 1] = o0[1]; out[3 * i0 + 2] = o0[2];
    }
}

extern "C" void kernel_launch(void* const* d_in, const int* in_sizes, int n_in,
                              void* d_out, int out_size, void* d_ws, size_t ws_size,
                              hipStream_t stream) {
    const float* x  = (const float*)d_in[0];
    const float* fm = (const float*)d_in[1];
    const float* W1 = (const float*)d_in[2];
    const float* b1 = (const float*)d_in[3];
    const float* W2 = (const float*)d_in[4];
    const float* b2 = (const float*)d_in[5];
    const float* W3 = (const float*)d_in[6];
    const float* b3 = (const float*)d_in[7];
    const float* W4 = (const float*)d_in[8];
    const float* b4 = (const float*)d_in[9];
    const float* W5 = (const float*)d_in[10];
    const float* b5 = (const float*)d_in[11];
    float* out = (float*)d_out;

    const int n = in_sizes[0] / 3;  // 4,000,000 points
    const long long threads = ((long long)n + 1) / 2;
    const int block = 256;
    const int grid = (int)((threads + block - 1) / block);

    const size_t need = (size_t)HWSZ * 4 * sizeof(float);  // 4 MB
    if (ws_size >= need) {
        float* fmT = (float*)d_ws;
        fm_transpose<<<(HWSZ + 255) / 256, 256, 0, stream>>>(fm, fmT);
        mlp_fused<true><<<grid, block, 0, stream>>>(x, fmT, W1, b1, W2, b2, W3, b3,
                                                    W4, b4, W5, b5, out, n);
    } else {
        mlp_fused<false><<<grid, block, 0, stream>>>(x, fm, W1, b1, W2, b2, W3, b3,
                                                     W4, b4, W5, b5, out, n);
    }
}